// Round 10
// baseline (648.760 us; speedup 1.0000x reference)
//
#include <hip/hip_runtime.h>
#include <stdint.h>

// KVCacheAttention: B=4, Sq=2048, Scache=6144, Skv=8192, D=1024, scale=1/8.
// Round 10: m97-structure GEMM -- 128x128xBK32, SINGLE-buffered 16 KB LDS,
// plain 2-barrier K-step (stage -> sync -> 16 MFMA -> sync), 4 waves (2x2,
// 64x64/wave). Low LDS+VGPR -> 6-8 resident blocks/CU (24-32 waves) so other
// blocks' MFMA covers each block's staging drain (the m97/m114 mechanism;
// r8 vs r9 proved block-count alone at 8 waves/CU does nothing -- this
// triples waves/CU). BK32 XOR swizzle slot^=(row&3)^((row>>2)&3) (2-way max,
// free). Round-7 operand-swapped coalesced epilogues. PV split-K(4).

#define DM 1024
#define NB 4
#define SQN 2048
#define SCC 6144
#define SKV 8192
#define NSPLIT 4
#define KSP (SKV / NSPLIT)

typedef unsigned short u16;
typedef __attribute__((ext_vector_type(8))) short short8;
typedef __attribute__((ext_vector_type(4))) float f32x4;

__device__ __forceinline__ u16 f2bf(float x) {
  unsigned u = __builtin_bit_cast(unsigned, x);
  u += 0x7fffu + ((u >> 16) & 1u);  // RNE; inputs finite
  return (u16)(u >> 16);
}

__device__ __forceinline__ void gll16(const void* g, void* l) {
  __builtin_amdgcn_global_load_lds(
      (const __attribute__((address_space(1))) void*)g,
      (__attribute__((address_space(3))) void*)l, 16, 0, 0);
}

// ---------------- conversions ----------------
__global__ __launch_bounds__(256) void k_cvt(const float* __restrict__ in,
                                             u16* __restrict__ out, long n4) {
  long i = (long)blockIdx.x * 256 + threadIdx.x;
  long st = (long)gridDim.x * 256;
  for (; i < n4; i += st) {
    float4 v = ((const float4*)in)[i];
    ushort4 u;
    u.x = f2bf(v.x); u.y = f2bf(v.y); u.z = f2bf(v.z); u.w = f2bf(v.w);
    ((ushort4*)out)[i] = u;
  }
}

// cached_key [4][6144][1024] f32 -> K bf16 [4][8192][1024] rows 0..6143
__global__ __launch_bounds__(256) void k_cvt_ck(const float* __restrict__ in,
                                                u16* __restrict__ out) {
  const long n4 = (long)NB * SCC * DM / 4;
  long i = (long)blockIdx.x * 256 + threadIdx.x;
  long st = (long)gridDim.x * 256;
  for (; i < n4; i += st) {
    float4 v = ((const float4*)in)[i];
    ushort4 u;
    u.x = f2bf(v.x); u.y = f2bf(v.y); u.z = f2bf(v.z); u.w = f2bf(v.w);
    long e = i * 4;
    int b = (int)(e / ((long)SCC * DM));
    long rem = e - (long)b * SCC * DM;
    *(ushort4*)(out + (long)b * SKV * DM + rem) = u;
  }
}

// ---------------- V^T builder ----------------
__global__ __launch_bounds__(256) void k_build_vt(const float* __restrict__ cv,
                                                  const u16* __restrict__ vtmp,
                                                  u16* __restrict__ VT) {
  __shared__ u16 t[64][65];
  const int kv0 = blockIdx.x * 64;
  const int d0 = blockIdx.y * 64;
  const int b = blockIdx.z;
  const int c = threadIdx.x & 63;
  const int r4 = threadIdx.x >> 6;
#pragma unroll
  for (int p = 0; p < 16; ++p) {
    int kr = p * 4 + r4;
    int kv = kv0 + kr;
    int d = d0 + c;
    u16 u;
    if (kv < SCC)
      u = f2bf(cv[((long)b * SCC + kv) * DM + d]);
    else
      u = vtmp[((long)b * SQN + (kv - SCC)) * DM + d];
    t[kr][c] = u;
  }
  __syncthreads();
#pragma unroll
  for (int p = 0; p < 16; ++p) {
    int dr = p * 4 + r4;
    VT[((long)b * DM + d0 + dr) * SKV + kv0 + c] = t[c][dr];
  }
}

// ---------------- 128x128xBK32 4-wave NT GEMM (high occupancy) ----------------
// 256 thr = 4 waves (2M x 2N); per-wave out 64x64; 16 MFMA/wave/K-step.
// LDS 16 KiB single-buffered: As[128][32] @0, Bs[128][32] @8192 (u16),
// XOR-swizzled on 16B slots: slot ^= (row&3)^((row>>2)&3), applied via
// pre-swizzled global source col (write dest linear: row=tid>>2, slot=tid&3).
template <int MODE>
__global__ __launch_bounds__(256) void k_gemm4(
    const u16* __restrict__ A, const u16* __restrict__ B0,
    void* __restrict__ C0, void* __restrict__ C1, void* __restrict__ C2,
    float* __restrict__ sums, const float* __restrict__ bias0,
    const float* __restrict__ bias1, const float* __restrict__ bias2) {
  __shared__ u16 As[128 * 32];
  __shared__ u16 Bs[128 * 32];
  const int tid = threadIdx.x;
  const int lane = tid & 63;
  const int wv = tid >> 6;   // 0..3
  const int wr = wv >> 1;    // 0..1
  const int wc = wv & 1;     // 0..1
  const int bm = blockIdx.y * 128;
  const int bn = blockIdx.x * 128;
  const int z = blockIdx.z;

  constexpr int LD = (MODE == 2) ? SKV : DM;
  constexpr int NT = ((MODE == 2) ? KSP : DM) / 32;

  const u16 *Ab_, *Bb_;
  if constexpr (MODE == 0) {
    Ab_ = A + (long)bm * LD;          // W-stack rows: out-d 0..3071
    Bb_ = B0 + (long)bn * LD;         // H tokens
  } else if constexpr (MODE == 1) {
    Ab_ = A + ((long)z * SKV + bm) * LD;   // K rows: kv
    Bb_ = B0 + ((long)z * SQN + bn) * LD;  // Q rows: q
  } else {
    const int bb_ = z >> 2, sp = z & 3;
    Ab_ = A + ((long)bb_ * SQN + bm) * (long)SKV + (long)sp * KSP;
    Bb_ = B0 + ((long)bb_ * DM + bn) * (long)SKV + (long)sp * KSP;
  }

  // staging: round r covers rows r*64 + (tid>>2); dest LDS linear tid*16B
  // (row=tid>>2, slot=tid&3); source col pre-swizzled:
  // col = (slot ^ (row&3) ^ ((row>>2)&3)) * 8 elems.
  const int srow = tid >> 2;
  const int scol = ((tid & 3) ^ ((tid >> 2) & 3) ^ ((tid >> 4) & 3)) * 8;
  const u16* gA = Ab_ + (long)srow * LD + scol;
  const u16* gB = Bb_ + (long)srow * LD + scol;
  u16* lA = As + tid * 8;
  u16* lB = Bs + tid * 8;

  f32x4 acc[4][4];
#pragma unroll
  for (int m = 0; m < 4; ++m)
#pragma unroll
    for (int n = 0; n < 4; ++n)
#pragma unroll
      for (int j = 0; j < 4; ++j) acc[m][n][j] = 0.0f;

  const int alane = lane & 15;
  // read slot: want col s0=lane>>4 of row base+alane:
  // slot = s0 ^ (row&3) ^ ((row>>2)&3) = (lane>>4) ^ (lane&3) ^ ((lane>>2)&3)
  const int slot8 = (((lane >> 4) ^ (lane & 3) ^ ((lane >> 2) & 3))) * 8;

#define AFRAG(M) (*(const short8*)&As[(wr * 64 + (M)*16 + alane) * 32 + slot8])
#define BFRAG(N) (*(const short8*)&Bs[(wc * 64 + (N)*16 + alane) * 32 + slot8])

  short8 aF[4], bF[4];

  for (int kt = 0; kt < NT; ++kt) {
    gll16(gA, lA);
    gll16(gA + (long)64 * LD, lA + 2048);
    gll16(gB, lB);
    gll16(gB + (long)64 * LD, lB + 2048);
    gA += 32;
    gB += 32;
    __syncthreads();  // drains vmcnt: tile ready (m97 rhythm; TLP covers)
#pragma unroll
    for (int m = 0; m < 4; ++m) aF[m] = AFRAG(m);
#pragma unroll
    for (int n = 0; n < 4; ++n) bF[n] = BFRAG(n);
    __builtin_amdgcn_s_setprio(1);
#pragma unroll
    for (int m = 0; m < 4; ++m)
#pragma unroll
      for (int n = 0; n < 4; ++n)
        acc[m][n] = __builtin_amdgcn_mfma_f32_16x16x32_bf16(aF[m], bF[n],
                                                            acc[m][n], 0, 0, 0);
    __builtin_amdgcn_s_setprio(0);
    __syncthreads();  // all reads done before next stage overwrites
  }
#undef AFRAG
#undef BFRAG

  // ---------------- epilogue (j-dim contiguous in output) ----------------
  const int rsub = (lane >> 4) * 4;

  if constexpr (MODE == 0) {
    // acc row = out-d, col = token. which = bm>>10 uniform per block.
    const int which = bm >> 10;
    const float* bp = which == 0 ? bias0 : (which == 1 ? bias1 : bias2);
    u16* Cq = (u16*)C0;
    u16* Ck = (u16*)C1;
    u16* Cv = (u16*)C2;
    const int od_base = (bm & 1023) + wr * 64 + rsub;
#pragma unroll
    for (int n = 0; n < 4; ++n) {
      int token = bn + wc * 64 + n * 16 + alane;
      u16* dst;
      if (which == 1) {
        int b = token >> 11, ss = token & 2047;
        dst = Ck + ((long)b * SKV + SCC + ss) * DM;
      } else if (which == 0) {
        dst = Cq + (long)token * DM;
      } else {
        dst = Cv + (long)token * DM;
      }
#pragma unroll
      for (int m = 0; m < 4; ++m) {
        int cc = od_base + m * 16;
        float4 bb = *(const float4*)(bp + cc);
        ushort4 u;
        u.x = f2bf(acc[m][n][0] + bb.x);
        u.y = f2bf(acc[m][n][1] + bb.y);
        u.z = f2bf(acc[m][n][2] + bb.z);
        u.w = f2bf(acc[m][n][3] + bb.w);
        *(ushort4*)(dst + cc) = u;
      }
    }
  } else if constexpr (MODE == 1) {
    // acc row = kv, col = q. store P[q][kv] ushort4; rowsum per q.
    u16* Pp = (u16*)C0 + (long)z * SQN * SKV;
    float* sb = sums + z * SQN;
    const float CE = 0.18033688011112042f;  // log2(e)/8
    const int kv_base = bm + wr * 64 + rsub;
#pragma unroll
    for (int n = 0; n < 4; ++n) {
      int q = bn + wc * 64 + n * 16 + alane;
      u16* prow = Pp + (long)q * SKV;
      float part = 0.f;
#pragma unroll
      for (int m = 0; m < 4; ++m) {
        int kv = kv_base + m * 16;
        float e0 = exp2f(acc[m][n][0] * CE);
        float e1 = exp2f(acc[m][n][1] * CE);
        float e2 = exp2f(acc[m][n][2] * CE);
        float e3 = exp2f(acc[m][n][3] * CE);
        part += (e0 + e1) + (e2 + e3);
        ushort4 u;
        u.x = f2bf(e0); u.y = f2bf(e1); u.z = f2bf(e2); u.w = f2bf(e3);
        *(ushort4*)(prow + kv) = u;
      }
      part += __shfl_xor(part, 16);
      part += __shfl_xor(part, 32);
      if ((lane >> 4) == 0) atomicAdd(&sb[q], part);
    }
  } else {
    // acc row = q, col = d. f32 stores, 64B segments per 16 lanes.
    float* Cp = (float*)C0 + (long)z * SQN * DM;
#pragma unroll
    for (int n = 0; n < 4; ++n) {
      int col = bn + wc * 64 + n * 16 + alane;
#pragma unroll
      for (int m = 0; m < 4; ++m)
#pragma unroll
        for (int j = 0; j < 4; ++j) {
          int row = bm + wr * 64 + m * 16 + rsub + j;
          Cp[(long)row * DM + col] = acc[m][n][j];
        }
    }
  }
}

// ---------------- reduce split-K(4) partials + normalize ----------------
__global__ __launch_bounds__(256) void k_reduce(const float* __restrict__ Op,
                                                const float* __restrict__ sums,
                                                float* __restrict__ out) {
  const long n4 = (long)NB * SQN * DM / 4;
  long i = (long)blockIdx.x * 256 + threadIdx.x;
  if (i >= n4) return;
  long e = i * 4;
  int b = (int)(e / ((long)SQN * DM));
  long rem = e - (long)b * SQN * DM;
  int row = (int)(rem / DM);
  const long z4 = (long)SQN * DM / 4;
  long i0 = (long)(b * NSPLIT) * z4 + (rem >> 2);
  float4 a0 = ((const float4*)Op)[i0];
  float4 a1 = ((const float4*)Op)[i0 + z4];
  float4 a2 = ((const float4*)Op)[i0 + 2 * z4];
  float4 a3 = ((const float4*)Op)[i0 + 3 * z4];
  float inv = 1.0f / sums[b * SQN + row];
  float4 r;
  r.x = ((a0.x + a1.x) + (a2.x + a3.x)) * inv;
  r.y = ((a0.y + a1.y) + (a2.y + a3.y)) * inv;
  r.z = ((a0.z + a1.z) + (a2.z + a3.z)) * inv;
  r.w = ((a0.w + a1.w) + (a2.w + a3.w)) * inv;
  ((float4*)out)[i] = r;
}

// ---------------- launch ----------------
extern "C" void kernel_launch(void* const* d_in, const int* in_sizes, int n_in,
                              void* d_out, int out_size, void* d_ws, size_t ws_size,
                              hipStream_t stream) {
  const float* hidden = (const float*)d_in[0];
  const float* ck = (const float*)d_in[1];
  const float* cv = (const float*)d_in[2];
  const float* Wq = (const float*)d_in[3];
  const float* bq = (const float*)d_in[4];
  const float* Wk = (const float*)d_in[5];
  const float* bk = (const float*)d_in[6];
  const float* Wv = (const float*)d_in[7];
  const float* bv = (const float*)d_in[8];
  (void)in_sizes; (void)n_in; (void)out_size; (void)ws_size;

  char* base = (char*)d_ws;
  size_t off = 0;
  auto alloc = [&](size_t bytes) {
    char* p = base + off;
    off = (off + bytes + 255) & ~(size_t)255;
    return p;
  };
  // region0 (dead before PV): Hb, weights, Qb, Kb, Vtmp. Opart aliases it.
  u16* Hb = (u16*)alloc((size_t)NB * SQN * DM * 2);
  u16* Wall = (u16*)alloc((size_t)3 * DM * DM * 2);  // Wq|Wk|Wv stacked
  u16* Qb = (u16*)alloc((size_t)NB * SQN * DM * 2);
  u16* Kb = (u16*)alloc((size_t)NB * SKV * DM * 2);
  u16* Vtmp = (u16*)alloc((size_t)NB * SQN * DM * 2);
  float* Opart = (float*)base;  // [NB*NSPLIT][2048][1024] f32, aliases region0
  size_t opart_bytes = (size_t)NB * NSPLIT * SQN * DM * 4;
  if (off < opart_bytes) off = (opart_bytes + 255) & ~(size_t)255;
  u16* VT = (u16*)alloc((size_t)NB * DM * SKV * 2);
  u16* P = (u16*)alloc((size_t)NB * SQN * SKV * 2);
  float* sums = (float*)alloc((size_t)NB * SQN * 4);

  // conversions
  k_cvt<<<2048, 256, 0, stream>>>(hidden, Hb, (long)NB * SQN * DM / 4);
  k_cvt<<<512, 256, 0, stream>>>(Wq, Wall, (long)DM * DM / 4);
  k_cvt<<<512, 256, 0, stream>>>(Wk, Wall + (size_t)DM * DM, (long)DM * DM / 4);
  k_cvt<<<512, 256, 0, stream>>>(Wv, Wall + (size_t)2 * DM * DM, (long)DM * DM / 4);
  k_cvt_ck<<<4096, 256, 0, stream>>>(ck, Kb);

  // fused QKV projection: A=W-stack [3072][1024], B=H [8192][1024]
  k_gemm4<0><<<dim3(64, 24, 1), 256, 0, stream>>>(
      Wall, Hb, Qb, Kb, Vtmp, nullptr, bq, bk, bv);

  // V^T
  k_build_vt<<<dim3(SKV / 64, DM / 64, NB), 256, 0, stream>>>(cv, Vtmp, VT);

  // S^T = K.Q^T with fused exp + row sums (batched over 4): A=K, B=Q
  hipMemsetAsync(sums, 0, (size_t)NB * SQN * 4, stream);
  k_gemm4<1><<<dim3(SQN / 128, SKV / 128, NB), 256, 0, stream>>>(
      Kb, Qb, P, nullptr, nullptr, sums, nullptr, nullptr, nullptr);

  // PV split-K(4): z = (b<<2)|split
  k_gemm4<2><<<dim3(DM / 128, SQN / 128, NB * NSPLIT), 256, 0, stream>>>(
      P, VT, Opart, nullptr, nullptr, nullptr, nullptr, nullptr, nullptr);

  // reduce partials + normalize
  k_reduce<<<(NB * SQN * DM / 4 + 255) / 256, 256, 0, stream>>>(
      Opart, sums, (float*)d_out);
}

// Round 11
// 623.151 us; speedup vs baseline: 1.0411x; 1.0411x over previous
//
#include <hip/hip_runtime.h>
#include <stdint.h>

// KVCacheAttention: B=4, Sq=2048, Scache=6144, Skv=8192, D=1024, scale=1/8.
// Round 11: 256x128 block tile, 8 waves of 64x64 (acc=64 regs -> room for
// >2 waves/SIMD), BK64 SINGLE-buffered 48 KB LDS -> 2+ blocks/CU. m97
// 2-barrier rhythm (syncthreads drain covered by co-resident block, m114),
// row&7 XOR swizzle (0 conflicts, 128B rows), setprio, round-7 coalesced
// operand-swapped epilogues. PV split-K(2).

#define DM 1024
#define NB 4
#define SQN 2048
#define SCC 6144
#define SKV 8192
#define NSPLIT 2
#define KSP (SKV / NSPLIT)

typedef unsigned short u16;
typedef __attribute__((ext_vector_type(8))) short short8;
typedef __attribute__((ext_vector_type(4))) float f32x4;

__device__ __forceinline__ u16 f2bf(float x) {
  unsigned u = __builtin_bit_cast(unsigned, x);
  u += 0x7fffu + ((u >> 16) & 1u);  // RNE; inputs finite
  return (u16)(u >> 16);
}

__device__ __forceinline__ void gll16(const void* g, void* l) {
  __builtin_amdgcn_global_load_lds(
      (const __attribute__((address_space(1))) void*)g,
      (__attribute__((address_space(3))) void*)l, 16, 0, 0);
}

// ---------------- conversions ----------------
__global__ __launch_bounds__(256) void k_cvt(const float* __restrict__ in,
                                             u16* __restrict__ out, long n4) {
  long i = (long)blockIdx.x * 256 + threadIdx.x;
  long st = (long)gridDim.x * 256;
  for (; i < n4; i += st) {
    float4 v = ((const float4*)in)[i];
    ushort4 u;
    u.x = f2bf(v.x); u.y = f2bf(v.y); u.z = f2bf(v.z); u.w = f2bf(v.w);
    ((ushort4*)out)[i] = u;
  }
}

// cached_key [4][6144][1024] f32 -> K bf16 [4][8192][1024] rows 0..6143
__global__ __launch_bounds__(256) void k_cvt_ck(const float* __restrict__ in,
                                                u16* __restrict__ out) {
  const long n4 = (long)NB * SCC * DM / 4;
  long i = (long)blockIdx.x * 256 + threadIdx.x;
  long st = (long)gridDim.x * 256;
  for (; i < n4; i += st) {
    float4 v = ((const float4*)in)[i];
    ushort4 u;
    u.x = f2bf(v.x); u.y = f2bf(v.y); u.z = f2bf(v.z); u.w = f2bf(v.w);
    long e = i * 4;
    int b = (int)(e / ((long)SCC * DM));
    long rem = e - (long)b * SCC * DM;
    *(ushort4*)(out + (long)b * SKV * DM + rem) = u;
  }
}

// ---------------- V^T builder ----------------
__global__ __launch_bounds__(256) void k_build_vt(const float* __restrict__ cv,
                                                  const u16* __restrict__ vtmp,
                                                  u16* __restrict__ VT) {
  __shared__ u16 t[64][65];
  const int kv0 = blockIdx.x * 64;
  const int d0 = blockIdx.y * 64;
  const int b = blockIdx.z;
  const int c = threadIdx.x & 63;
  const int r4 = threadIdx.x >> 6;
#pragma unroll
  for (int p = 0; p < 16; ++p) {
    int kr = p * 4 + r4;
    int kv = kv0 + kr;
    int d = d0 + c;
    u16 u;
    if (kv < SCC)
      u = f2bf(cv[((long)b * SCC + kv) * DM + d]);
    else
      u = vtmp[((long)b * SQN + (kv - SCC)) * DM + d];
    t[kr][c] = u;
  }
  __syncthreads();
#pragma unroll
  for (int p = 0; p < 16; ++p) {
    int dr = p * 4 + r4;
    VT[((long)b * DM + d0 + dr) * SKV + kv0 + c] = t[c][dr];
  }
}

// ---------------- 256x128xBK64 8-wave NT GEMM (single-buffer, 2+ blk/CU) ----
// 512 thr = 8 waves (4 x wr over A-rows, 2 x wc over B-rows); per-wave 64x64.
// LDS 48 KiB: As[256][64] u16 @0 (32KB), Bs[128][64] @32KB (16KB),
// XOR-swizzled (16B slot ^= row&7) via pre-swizzled global source col.
// K-step: sync (drains staging vmcnt); read+MFMA kk0; read+MFMA kk1; sync;
// stage next tile (6 x gll16). Cross-block TLP covers the drain.
template <int MODE>
__global__ __launch_bounds__(512, 2) void k_gemm(
    const u16* __restrict__ A, const u16* __restrict__ B0,
    void* __restrict__ C0, void* __restrict__ C1, void* __restrict__ C2,
    float* __restrict__ sums, const float* __restrict__ bias0,
    const float* __restrict__ bias1, const float* __restrict__ bias2) {
  extern __shared__ char smem[];
  const int tid = threadIdx.x;
  const int lane = tid & 63;
  const int wv = tid >> 6;   // 0..7
  const int wr = wv >> 1;    // 0..3 (A-row band)
  const int wc = wv & 1;     // 0..1 (B-row half)
  const int bm = blockIdx.y * 256;   // A rows
  const int bn = blockIdx.x * 128;   // B rows
  const int z = blockIdx.z;

  constexpr int LD = (MODE == 2) ? SKV : DM;
  constexpr int NT = ((MODE == 2) ? KSP : DM) / 64;

  const u16 *Ab_, *Bb_;
  if constexpr (MODE == 0) {
    Ab_ = A + (long)bm * LD;          // W-stack rows: out-d 0..3071
    Bb_ = B0 + (long)bn * LD;         // H tokens
  } else if constexpr (MODE == 1) {
    Ab_ = A + ((long)z * SKV + bm) * LD;   // K rows: kv
    Bb_ = B0 + ((long)z * SQN + bn) * LD;  // Q rows: q
  } else {
    const int bb_ = z / NSPLIT, sp = z % NSPLIT;
    Ab_ = A + ((long)bb_ * SQN + bm) * (long)SKV + (long)sp * KSP;
    Bb_ = B0 + ((long)bb_ * DM + bn) * (long)SKV + (long)sp * KSP;
  }

  // staging: round covers 64 rows; wave wv stages rows wv*8+(lane>>3);
  // global col pre-swizzled so linear LDS write produces the swizzled tile.
  const int srow = wv * 8 + (lane >> 3);
  const int scol = ((lane & 7) ^ (lane >> 3)) * 8;
  const u16* gA = Ab_ + (long)srow * LD + scol;
  const u16* gB = Bb_ + (long)srow * LD + scol;
  u16* lA = (u16*)smem + wv * 512 + lane * 8;          // + r*4096
  u16* lB = (u16*)smem + 16384 + wv * 512 + lane * 8;  // + r*4096

  // prologue: stage tile 0 (A: 4 rounds, B: 2 rounds)
#pragma unroll
  for (int r = 0; r < 4; ++r) gll16(gA + (long)r * 64 * LD, lA + r * 4096);
#pragma unroll
  for (int r = 0; r < 2; ++r) gll16(gB + (long)r * 64 * LD, lB + r * 4096);

  f32x4 acc[4][4];
#pragma unroll
  for (int m = 0; m < 4; ++m)
#pragma unroll
    for (int n = 0; n < 4; ++n)
#pragma unroll
      for (int j = 0; j < 4; ++j) acc[m][n][j] = 0.0f;

  const int alane = lane & 15;
  const int sw = lane & 7;   // row&7 == lane&7 for all frag rows
  const int s0 = lane >> 4;  // base 16B slot

#define AFRAG(M, KK)                                                  \
  (*(const short8*)(As + (wr * 64 + (M)*16 + alane) * 128 +           \
                    (((s0 + 4 * (KK)) ^ sw) * 16)))
#define BFRAG(N, KK)                                                  \
  (*(const short8*)(Bs + (wc * 64 + (N)*16 + alane) * 128 +           \
                    (((s0 + 4 * (KK)) ^ sw) * 16)))

  short8 aF[4], bF[4];

  for (int kt = 0; kt < NT; ++kt) {
    const char* As = smem;
    const char* Bs = smem + 32768;
    __syncthreads();  // staging visible (drains vmcnt; other block covers)
#pragma unroll
    for (int kk = 0; kk < 2; ++kk) {
#pragma unroll
      for (int m = 0; m < 4; ++m) aF[m] = AFRAG(m, kk);
#pragma unroll
      for (int n = 0; n < 4; ++n) bF[n] = BFRAG(n, kk);
      __builtin_amdgcn_s_setprio(1);
#pragma unroll
      for (int m = 0; m < 4; ++m)
#pragma unroll
        for (int n = 0; n < 4; ++n)
          acc[m][n] = __builtin_amdgcn_mfma_f32_16x16x32_bf16(
              aF[m], bF[n], acc[m][n], 0, 0, 0);
      __builtin_amdgcn_s_setprio(0);
    }
    __syncthreads();  // all reads done before restage
    if (kt + 1 < NT) {
      const long ko = (long)(kt + 1) * 64;
#pragma unroll
      for (int r = 0; r < 4; ++r)
        gll16(gA + ko + (long)r * 64 * LD, lA + r * 4096);
#pragma unroll
      for (int r = 0; r < 2; ++r)
        gll16(gB + ko + (long)r * 64 * LD, lB + r * 4096);
    }
  }
#undef AFRAG
#undef BFRAG

  // ---------------- epilogue (j-dim contiguous in output) ----------------
  const int rsub = (lane >> 4) * 4;

  if constexpr (MODE == 0) {
    // acc row = out-d, col = token. which = bm>>10 uniform per block.
    const int which = bm >> 10;
    const float* bp = which == 0 ? bias0 : (which == 1 ? bias1 : bias2);
    u16* Cq = (u16*)C0;
    u16* Ck = (u16*)C1;
    u16* Cv = (u16*)C2;
    const int od_base = (bm & 1023) + wr * 64 + rsub;
#pragma unroll
    for (int n = 0; n < 4; ++n) {
      int token = bn + wc * 64 + n * 16 + alane;
      u16* dst;
      if (which == 1) {
        int b = token >> 11, ss = token & 2047;
        dst = Ck + ((long)b * SKV + SCC + ss) * DM;
      } else if (which == 0) {
        dst = Cq + (long)token * DM;
      } else {
        dst = Cv + (long)token * DM;
      }
#pragma unroll
      for (int m = 0; m < 4; ++m) {
        int cc = od_base + m * 16;
        float4 bb = *(const float4*)(bp + cc);
        ushort4 u;
        u.x = f2bf(acc[m][n][0] + bb.x);
        u.y = f2bf(acc[m][n][1] + bb.y);
        u.z = f2bf(acc[m][n][2] + bb.z);
        u.w = f2bf(acc[m][n][3] + bb.w);
        *(ushort4*)(dst + cc) = u;
      }
    }
  } else if constexpr (MODE == 1) {
    // acc row = kv, col = q. store P[q][kv] ushort4; rowsum per q.
    u16* Pp = (u16*)C0 + (long)z * SQN * SKV;
    float* sb = sums + z * SQN;
    const float CE = 0.18033688011112042f;  // log2(e)/8
    const int kv_base = bm + wr * 64 + rsub;
#pragma unroll
    for (int n = 0; n < 4; ++n) {
      int q = bn + wc * 64 + n * 16 + alane;
      u16* prow = Pp + (long)q * SKV;
      float part = 0.f;
#pragma unroll
      for (int m = 0; m < 4; ++m) {
        int kv = kv_base + m * 16;
        float e0 = exp2f(acc[m][n][0] * CE);
        float e1 = exp2f(acc[m][n][1] * CE);
        float e2 = exp2f(acc[m][n][2] * CE);
        float e3 = exp2f(acc[m][n][3] * CE);
        part += (e0 + e1) + (e2 + e3);
        ushort4 u;
        u.x = f2bf(e0); u.y = f2bf(e1); u.z = f2bf(e2); u.w = f2bf(e3);
        *(ushort4*)(prow + kv) = u;
      }
      part += __shfl_xor(part, 16);
      part += __shfl_xor(part, 32);
      if ((lane >> 4) == 0) atomicAdd(&sb[q], part);
    }
  } else {
    // acc row = q, col = d. f32 stores, 64B segments per 16 lanes.
    float* Cp = (float*)C0 + (long)z * SQN * DM;
#pragma unroll
    for (int n = 0; n < 4; ++n) {
      int col = bn + wc * 64 + n * 16 + alane;
#pragma unroll
      for (int m = 0; m < 4; ++m)
#pragma unroll
        for (int j = 0; j < 4; ++j) {
          int row = bm + wr * 64 + m * 16 + rsub + j;
          Cp[(long)row * DM + col] = acc[m][n][j];
        }
    }
  }
}

// ---------------- reduce split-K partials + normalize ----------------
__global__ __launch_bounds__(256) void k_reduce(const float* __restrict__ Op,
                                                const float* __restrict__ sums,
                                                float* __restrict__ out) {
  const long n4 = (long)NB * SQN * DM / 4;
  long i = (long)blockIdx.x * 256 + threadIdx.x;
  if (i >= n4) return;
  long e = i * 4;
  int b = (int)(e / ((long)SQN * DM));
  long rem = e - (long)b * SQN * DM;
  int row = (int)(rem / DM);
  const long z4 = (long)SQN * DM / 4;
  long i0 = (long)(b * NSPLIT) * z4 + (rem >> 2);
  float4 a0 = ((const float4*)Op)[i0];
  float4 a1 = ((const float4*)Op)[i0 + z4];
  float inv = 1.0f / sums[b * SQN + row];
  float4 r;
  r.x = (a0.x + a1.x) * inv;
  r.y = (a0.y + a1.y) * inv;
  r.z = (a0.z + a1.z) * inv;
  r.w = (a0.w + a1.w) * inv;
  ((float4*)out)[i] = r;
}

// ---------------- launch ----------------
extern "C" void kernel_launch(void* const* d_in, const int* in_sizes, int n_in,
                              void* d_out, int out_size, void* d_ws, size_t ws_size,
                              hipStream_t stream) {
  const float* hidden = (const float*)d_in[0];
  const float* ck = (const float*)d_in[1];
  const float* cv = (const float*)d_in[2];
  const float* Wq = (const float*)d_in[3];
  const float* bq = (const float*)d_in[4];
  const float* Wk = (const float*)d_in[5];
  const float* bk = (const float*)d_in[6];
  const float* Wv = (const float*)d_in[7];
  const float* bv = (const float*)d_in[8];
  (void)in_sizes; (void)n_in; (void)out_size; (void)ws_size;

  hipFuncSetAttribute(reinterpret_cast<const void*>(&k_gemm<0>),
                      hipFuncAttributeMaxDynamicSharedMemorySize, 49152);
  hipFuncSetAttribute(reinterpret_cast<const void*>(&k_gemm<1>),
                      hipFuncAttributeMaxDynamicSharedMemorySize, 49152);
  hipFuncSetAttribute(reinterpret_cast<const void*>(&k_gemm<2>),
                      hipFuncAttributeMaxDynamicSharedMemorySize, 49152);

  char* base = (char*)d_ws;
  size_t off = 0;
  auto alloc = [&](size_t bytes) {
    char* p = base + off;
    off = (off + bytes + 255) & ~(size_t)255;
    return p;
  };
  // region0 (dead before PV): Hb, weights, Qb, Kb, Vtmp. Opart aliases it.
  u16* Hb = (u16*)alloc((size_t)NB * SQN * DM * 2);
  u16* Wall = (u16*)alloc((size_t)3 * DM * DM * 2);  // Wq|Wk|Wv stacked
  u16* Qb = (u16*)alloc((size_t)NB * SQN * DM * 2);
  u16* Kb = (u16*)alloc((size_t)NB * SKV * DM * 2);
  u16* Vtmp = (u16*)alloc((size_t)NB * SQN * DM * 2);
  float* Opart = (float*)base;  // [NB*NSPLIT][2048][1024] f32, aliases region0
  size_t opart_bytes = (size_t)NB * NSPLIT * SQN * DM * 4;
  if (off < opart_bytes) off = (opart_bytes + 255) & ~(size_t)255;
  u16* VT = (u16*)alloc((size_t)NB * DM * SKV * 2);
  u16* P = (u16*)alloc((size_t)NB * SQN * SKV * 2);
  float* sums = (float*)alloc((size_t)NB * SQN * 4);

  // conversions
  k_cvt<<<2048, 256, 0, stream>>>(hidden, Hb, (long)NB * SQN * DM / 4);
  k_cvt<<<512, 256, 0, stream>>>(Wq, Wall, (long)DM * DM / 4);
  k_cvt<<<512, 256, 0, stream>>>(Wk, Wall + (size_t)DM * DM, (long)DM * DM / 4);
  k_cvt<<<512, 256, 0, stream>>>(Wv, Wall + (size_t)2 * DM * DM, (long)DM * DM / 4);
  k_cvt_ck<<<4096, 256, 0, stream>>>(ck, Kb);

  // fused QKV projection: A=W-stack [3072][1024], B=H [8192][1024]
  k_gemm<0><<<dim3(64, 12, 1), 512, 49152, stream>>>(
      Wall, Hb, Qb, Kb, Vtmp, nullptr, bq, bk, bv);

  // V^T
  k_build_vt<<<dim3(SKV / 64, DM / 64, NB), 256, 0, stream>>>(cv, Vtmp, VT);

  // S^T = K.Q^T with fused exp + row sums (batched over 4): A=K, B=Q
  hipMemsetAsync(sums, 0, (size_t)NB * SQN * 4, stream);
  k_gemm<1><<<dim3(SQN / 128, SKV / 256, NB), 512, 49152, stream>>>(
      Kb, Qb, P, nullptr, nullptr, sums, nullptr, nullptr, nullptr);

  // PV split-K(2): A=P [q, kv], B=VT [d, kv], z = b*NSPLIT + split
  k_gemm<2><<<dim3(DM / 128, SQN / 256, NB * NSPLIT), 512, 49152, stream>>>(
      P, VT, Opart, nullptr, nullptr, nullptr, nullptr, nullptr, nullptr);

  // reduce partials + normalize
  k_reduce<<<(NB * SQN * DM / 4 + 255) / 256, 256, 0, stream>>>(
      Opart, sums, (float*)d_out);
}

// Round 12
// 515.602 us; speedup vs baseline: 1.2583x; 1.2086x over previous
//
#include <hip/hip_runtime.h>
#include <stdint.h>

// KVCacheAttention: B=4, Sq=2048, Scache=6144, Skv=8192, D=1024, scale=1/8.
// Round 12: round-8 K-loop (best measured) + operand roles reverted to r1/r3
// (A = output-row operand) so epilogue stores are SECTOR-FULL (16 lanes cover
// 32B contiguous of one output row). r7/r8's ushort4 stores fragmented 32B
// sectors (8B/row) -> write-allocate refetched P (~165MB extra FETCH).
// MODE0: A=H, B=W-stack. MODE1: A=Q, B=K, grid x=kv fastest (r3's 105MB
// traversal). MODE2 PV unchanged.

#define DM 1024
#define NB 4
#define SQN 2048
#define SCC 6144
#define SKV 8192
#define NSPLIT 2
#define KSP (SKV / NSPLIT)

typedef unsigned short u16;
typedef __attribute__((ext_vector_type(8))) short short8;
typedef __attribute__((ext_vector_type(4))) float f32x4;

__device__ __forceinline__ u16 f2bf(float x) {
  unsigned u = __builtin_bit_cast(unsigned, x);
  u += 0x7fffu + ((u >> 16) & 1u);  // RNE; inputs finite
  return (u16)(u >> 16);
}

__device__ __forceinline__ void gll16(const void* g, void* l) {
  __builtin_amdgcn_global_load_lds(
      (const __attribute__((address_space(1))) void*)g,
      (__attribute__((address_space(3))) void*)l, 16, 0, 0);
}

#define FENCE() asm volatile("" ::: "memory")
#define BARRIER()                      \
  do {                                 \
    FENCE();                           \
    __builtin_amdgcn_s_barrier();      \
    FENCE();                           \
  } while (0)

#define DSR(d, a, I) \
  asm volatile("ds_read_b128 %0, %1 offset:" #I : "=v"(d) : "v"(a))

#define LGKM(N)                                   \
  do {                                            \
    asm volatile("s_waitcnt lgkmcnt(" #N ")");    \
    __builtin_amdgcn_sched_barrier(0);            \
  } while (0)

#define MFMAQ(AF, BF, MB)                                                   \
  do {                                                                      \
    __builtin_amdgcn_s_setprio(1);                                          \
    _Pragma("unroll") for (int m = 0; m < 4; ++m)                           \
        _Pragma("unroll") for (int n = 0; n < 4; ++n) acc[(MB) + m][n] =    \
        __builtin_amdgcn_mfma_f32_16x16x32_bf16(AF[m], BF[n],               \
                                                acc[(MB) + m][n], 0, 0, 0); \
    __builtin_amdgcn_s_setprio(0);                                          \
    __builtin_amdgcn_sched_barrier(0);                                      \
  } while (0)

// ---------------- conversions ----------------
__global__ __launch_bounds__(256) void k_cvt(const float* __restrict__ in,
                                             u16* __restrict__ out, long n4) {
  long i = (long)blockIdx.x * 256 + threadIdx.x;
  long st = (long)gridDim.x * 256;
  for (; i < n4; i += st) {
    float4 v = ((const float4*)in)[i];
    ushort4 u;
    u.x = f2bf(v.x); u.y = f2bf(v.y); u.z = f2bf(v.z); u.w = f2bf(v.w);
    ((ushort4*)out)[i] = u;
  }
}

// cached_key [4][6144][1024] f32 -> K bf16 [4][8192][1024] rows 0..6143
__global__ __launch_bounds__(256) void k_cvt_ck(const float* __restrict__ in,
                                                u16* __restrict__ out) {
  const long n4 = (long)NB * SCC * DM / 4;
  long i = (long)blockIdx.x * 256 + threadIdx.x;
  long st = (long)gridDim.x * 256;
  for (; i < n4; i += st) {
    float4 v = ((const float4*)in)[i];
    ushort4 u;
    u.x = f2bf(v.x); u.y = f2bf(v.y); u.z = f2bf(v.z); u.w = f2bf(v.w);
    long e = i * 4;
    int b = (int)(e / ((long)SCC * DM));
    long rem = e - (long)b * SCC * DM;
    *(ushort4*)(out + (long)b * SKV * DM + rem) = u;
  }
}

// ---------------- V^T builder ----------------
__global__ __launch_bounds__(256) void k_build_vt(const float* __restrict__ cv,
                                                  const u16* __restrict__ vtmp,
                                                  u16* __restrict__ VT) {
  __shared__ u16 t[64][65];
  const int kv0 = blockIdx.x * 64;
  const int d0 = blockIdx.y * 64;
  const int b = blockIdx.z;
  const int c = threadIdx.x & 63;
  const int r4 = threadIdx.x >> 6;
#pragma unroll
  for (int p = 0; p < 16; ++p) {
    int kr = p * 4 + r4;
    int kv = kv0 + kr;
    int d = d0 + c;
    u16 u;
    if (kv < SCC)
      u = f2bf(cv[((long)b * SCC + kv) * DM + d]);
    else
      u = vtmp[((long)b * SQN + (kv - SCC)) * DM + d];
    t[kr][c] = u;
  }
  __syncthreads();
#pragma unroll
  for (int p = 0; p < 16; ++p) {
    int dr = p * 4 + r4;
    VT[((long)b * DM + d0 + dr) * SKV + kv0 + c] = t[c][dr];
  }
}

// ---------------- 256x256xBK64 8-wave NT GEMM (r8 pipelined loop) ----------
// 512 thr = 8 waves (2M x 4N); per-wave out 128x64; BK=64 (2 kk-slices).
// LDS 128 KiB: A[2][256][64] @0, B[2][256][64] @65536, XOR-swizzled
// (16B slot ^= row&7) via pre-swizzled global source.
// MODE0: A=H tokens, B=Wq|Wk|Wv stack; routed bias epilogue, sector-full u16.
// MODE1: A=Q, B=K; P[q][kv] u16 (lanes cover 32B contiguous kv) + rowsums.
// MODE2: A=P, B=VT; split-K f32 partials (64B sectors).
template <int MODE>
__global__ __launch_bounds__(512, 2) void k_gemm8(
    const u16* __restrict__ A, const u16* __restrict__ B0,
    void* __restrict__ C0, void* __restrict__ C1, void* __restrict__ C2,
    float* __restrict__ sums, const float* __restrict__ bias0,
    const float* __restrict__ bias1, const float* __restrict__ bias2) {
  extern __shared__ char smem[];
  const int tid = threadIdx.x;
  const int lane = tid & 63;
  const int wv = tid >> 6;   // 0..7
  const int wr = wv >> 2;    // 0..1
  const int wc = wv & 3;     // 0..3
  const int bm = blockIdx.y * 256;  // A rows (output rows)
  const int bn = blockIdx.x * 256;  // B rows (output cols)
  const int z = blockIdx.z;

  constexpr int LD = (MODE == 2) ? SKV : DM;
  constexpr int NT = ((MODE == 2) ? KSP : DM) / 64;

  const u16 *Ab_, *Bb_;
  if constexpr (MODE == 0) {
    Ab_ = A + (long)bm * LD;          // H token rows
    Bb_ = B0 + (long)bn * LD;         // W-stack rows: out-d 0..3071
  } else if constexpr (MODE == 1) {
    Ab_ = A + ((long)z * SQN + bm) * LD;   // Q rows: q
    Bb_ = B0 + ((long)z * SKV + bn) * LD;  // K rows: kv
  } else {
    const int bb_ = z / NSPLIT, sp = z % NSPLIT;
    Ab_ = A + ((long)bb_ * SQN + bm) * (long)SKV + (long)sp * KSP;
    Bb_ = B0 + ((long)bb_ * DM + bn) * (long)SKV + (long)sp * KSP;
  }

  const int srow = wv * 8 + (lane >> 3);
  const int scol = ((lane & 7) ^ (lane >> 3)) * 8;
  const u16* gA = Ab_ + (long)srow * LD + scol;
  const u16* gB = Bb_ + (long)srow * LD + scol;
  u16* lA = (u16*)smem + wv * 512 + lane * 8;            // + buf*16384 + r*4096
  u16* lB = (u16*)(smem + 65536) + wv * 512 + lane * 8;

  // prologue: stage K-tile 0 into buf0
#pragma unroll
  for (int r = 0; r < 4; ++r) gll16(gA + (long)r * 64 * LD, lA + r * 4096);
#pragma unroll
  for (int r = 0; r < 4; ++r) gll16(gB + (long)r * 64 * LD, lB + r * 4096);

  f32x4 acc[8][4];
#pragma unroll
  for (int m = 0; m < 8; ++m)
#pragma unroll
    for (int n = 0; n < 4; ++n)
#pragma unroll
      for (int j = 0; j < 4; ++j) acc[m][n][j] = 0.0f;

  const int alane = lane & 15;
  const int sw = lane & 7;
  const int s0 = lane >> 4;
  const int slot0 = ((s0 ^ sw) * 16);
  const int slot1 = (((s0 + 4) ^ sw) * 16);
  const int arow_b = (wr * 128 + alane) * 128;
  const int brow_b = (wc * 64 + alane) * 128;

  short8 Aa[4], Abf[4], Bf0[4], Bf1[4];

  for (int kt = 0; kt < NT; ++kt) {
    const int bsel = (kt & 1) * 32768;
    const int d = ((kt & 1) ^ 1) * 16384;
    const long knext = (long)((kt + 1 < NT) ? kt + 1 : kt) * 64;
    const u16* gAn = gA + knext;
    const u16* gBn = gB + knext;
    const int a0 = bsel + arow_b + slot0;
    const int a1 = bsel + arow_b + slot1;
    const int b0 = 65536 + bsel + brow_b + slot0;
    const int b1 = 65536 + bsel + brow_b + slot1;

    // ---- ph0 ----
    gll16(gAn, lA + d);
    gll16(gAn + (long)64 * LD, lA + d + 4096);
    asm volatile("s_waitcnt vmcnt(2)" ::: "memory");
    BARRIER();
    DSR(Aa[0], a0, 0); DSR(Aa[1], a0, 2048);
    DSR(Aa[2], a0, 4096); DSR(Aa[3], a0, 6144);
    DSR(Bf0[0], b0, 0); DSR(Bf0[1], b0, 2048);
    DSR(Bf0[2], b0, 4096); DSR(Bf0[3], b0, 6144);
    DSR(Abf[0], a0, 8192); DSR(Abf[1], a0, 10240);
    DSR(Abf[2], a0, 12288); DSR(Abf[3], a0, 14336);
    LGKM(4);
    MFMAQ(Aa, Bf0, 0);
    BARRIER();

    // ---- ph1 ----
    DSR(Aa[0], a1, 0); DSR(Aa[1], a1, 2048);
    DSR(Aa[2], a1, 4096); DSR(Aa[3], a1, 6144);
    DSR(Bf1[0], b1, 0); DSR(Bf1[1], b1, 2048);
    DSR(Bf1[2], b1, 4096); DSR(Bf1[3], b1, 6144);
    gll16(gAn + (long)128 * LD, lA + d + 2 * 4096);
    gll16(gAn + (long)192 * LD, lA + d + 3 * 4096);
    BARRIER();
    LGKM(8);
    MFMAQ(Abf, Bf0, 4);
    BARRIER();

    // ---- ph2 ----
    DSR(Abf[0], a1, 8192); DSR(Abf[1], a1, 10240);
    DSR(Abf[2], a1, 12288); DSR(Abf[3], a1, 14336);
    gll16(gBn, lB + d);
    gll16(gBn + (long)64 * LD, lB + d + 4096);
    BARRIER();
    LGKM(4);
    MFMAQ(Aa, Bf1, 0);
    BARRIER();

    // ---- ph3 ----
    gll16(gBn + (long)128 * LD, lB + d + 2 * 4096);
    gll16(gBn + (long)192 * LD, lB + d + 3 * 4096);
    BARRIER();
    LGKM(0);
    MFMAQ(Abf, Bf1, 4);
    BARRIER();
  }

  // ---------------- epilogue (sector-full stores) ----------------
  const int rsub = (lane >> 4) * 4;

  if constexpr (MODE == 0) {
    // acc row = token, col = out-d. 16 lanes -> 32B contiguous out-d.
    const int which = bn >> 10;
    const float* bp = which == 0 ? bias0 : (which == 1 ? bias1 : bias2);
    u16* Cq = (u16*)C0;
    u16* Ck = (u16*)C1;
    u16* Cv = (u16*)C2;
    const int token_base = bm + wr * 128 + rsub;
    const int cc0 = (bn & 1023) + wc * 64 + alane;
#pragma unroll
    for (int n = 0; n < 4; ++n) {
      int cc = cc0 + n * 16;
      float bb = bp[cc];
#pragma unroll
      for (int m = 0; m < 8; ++m)
#pragma unroll
        for (int j = 0; j < 4; ++j) {
          int token = token_base + m * 16 + j;
          u16 hv = f2bf(acc[m][n][j] + bb);
          if (which == 1) {
            int b = token >> 11, ss = token & 2047;
            Ck[((long)b * SKV + SCC + ss) * DM + cc] = hv;
          } else if (which == 0) {
            Cq[(long)token * DM + cc] = hv;
          } else {
            Cv[(long)token * DM + cc] = hv;
          }
        }
    }
  } else if constexpr (MODE == 1) {
    // acc row = q, col = kv. 16 lanes -> 32B contiguous kv of one q-row.
    u16* Pp = (u16*)C0 + (long)z * SQN * SKV;
    float* sb = sums + z * SQN;
    const float CE = 0.18033688011112042f;  // log2(e)/8
    const int q_base = bm + wr * 128 + rsub;
    const int kv0 = bn + wc * 64 + alane;
#pragma unroll
    for (int m = 0; m < 8; ++m)
#pragma unroll
      for (int j = 0; j < 4; ++j) {
        int q = q_base + m * 16 + j;
        u16* prow = Pp + (long)q * SKV;
        float part = 0.f;
#pragma unroll
        for (int n = 0; n < 4; ++n) {
          float e = exp2f(acc[m][n][j] * CE);
          part += e;
          prow[kv0 + n * 16] = f2bf(e);
        }
        part += __shfl_xor(part, 1);
        part += __shfl_xor(part, 2);
        part += __shfl_xor(part, 4);
        part += __shfl_xor(part, 8);
        if (alane == 0) atomicAdd(&sb[q], part);
      }
  } else {
    // acc row = q, col = d. f32 stores, 64B sectors.
    float* Cp = (float*)C0 + (long)z * SQN * DM;
#pragma unroll
    for (int n = 0; n < 4; ++n) {
      int col = bn + wc * 64 + n * 16 + alane;
#pragma unroll
      for (int m = 0; m < 8; ++m)
#pragma unroll
        for (int j = 0; j < 4; ++j) {
          int row = bm + wr * 128 + m * 16 + rsub + j;
          Cp[(long)row * DM + col] = acc[m][n][j];
        }
    }
  }
}

// ---------------- reduce split-K partials + normalize ----------------
__global__ __launch_bounds__(256) void k_reduce(const float* __restrict__ Op,
                                                const float* __restrict__ sums,
                                                float* __restrict__ out) {
  const long n4 = (long)NB * SQN * DM / 4;
  long i = (long)blockIdx.x * 256 + threadIdx.x;
  if (i >= n4) return;
  long e = i * 4;
  int b = (int)(e / ((long)SQN * DM));
  long rem = e - (long)b * SQN * DM;
  int row = (int)(rem / DM);
  const long z4 = (long)SQN * DM / 4;
  long i0 = (long)(b * NSPLIT) * z4 + (rem >> 2);
  float4 a0 = ((const float4*)Op)[i0];
  float4 a1 = ((const float4*)Op)[i0 + z4];
  float inv = 1.0f / sums[b * SQN + row];
  float4 r;
  r.x = (a0.x + a1.x) * inv;
  r.y = (a0.y + a1.y) * inv;
  r.z = (a0.z + a1.z) * inv;
  r.w = (a0.w + a1.w) * inv;
  ((float4*)out)[i] = r;
}

// ---------------- launch ----------------
extern "C" void kernel_launch(void* const* d_in, const int* in_sizes, int n_in,
                              void* d_out, int out_size, void* d_ws, size_t ws_size,
                              hipStream_t stream) {
  const float* hidden = (const float*)d_in[0];
  const float* ck = (const float*)d_in[1];
  const float* cv = (const float*)d_in[2];
  const float* Wq = (const float*)d_in[3];
  const float* bq = (const float*)d_in[4];
  const float* Wk = (const float*)d_in[5];
  const float* bk = (const float*)d_in[6];
  const float* Wv = (const float*)d_in[7];
  const float* bv = (const float*)d_in[8];
  (void)in_sizes; (void)n_in; (void)out_size; (void)ws_size;

  hipFuncSetAttribute(reinterpret_cast<const void*>(&k_gemm8<0>),
                      hipFuncAttributeMaxDynamicSharedMemorySize, 131072);
  hipFuncSetAttribute(reinterpret_cast<const void*>(&k_gemm8<1>),
                      hipFuncAttributeMaxDynamicSharedMemorySize, 131072);
  hipFuncSetAttribute(reinterpret_cast<const void*>(&k_gemm8<2>),
                      hipFuncAttributeMaxDynamicSharedMemorySize, 131072);

  char* base = (char*)d_ws;
  size_t off = 0;
  auto alloc = [&](size_t bytes) {
    char* p = base + off;
    off = (off + bytes + 255) & ~(size_t)255;
    return p;
  };
  // region0 (dead before PV): Hb, weights, Qb, Kb, Vtmp. Opart aliases it.
  u16* Hb = (u16*)alloc((size_t)NB * SQN * DM * 2);
  u16* Wall = (u16*)alloc((size_t)3 * DM * DM * 2);  // Wq|Wk|Wv stacked
  u16* Qb = (u16*)alloc((size_t)NB * SQN * DM * 2);
  u16* Kb = (u16*)alloc((size_t)NB * SKV * DM * 2);
  u16* Vtmp = (u16*)alloc((size_t)NB * SQN * DM * 2);
  float* Opart = (float*)base;  // [NB*NSPLIT][2048][1024] f32, aliases region0
  size_t opart_bytes = (size_t)NB * NSPLIT * SQN * DM * 4;
  if (off < opart_bytes) off = (opart_bytes + 255) & ~(size_t)255;
  u16* VT = (u16*)alloc((size_t)NB * DM * SKV * 2);
  u16* P = (u16*)alloc((size_t)NB * SQN * SKV * 2);
  float* sums = (float*)alloc((size_t)NB * SQN * 4);

  // conversions
  k_cvt<<<2048, 256, 0, stream>>>(hidden, Hb, (long)NB * SQN * DM / 4);
  k_cvt<<<512, 256, 0, stream>>>(Wq, Wall, (long)DM * DM / 4);
  k_cvt<<<512, 256, 0, stream>>>(Wk, Wall + (size_t)DM * DM, (long)DM * DM / 4);
  k_cvt<<<512, 256, 0, stream>>>(Wv, Wall + (size_t)2 * DM * DM, (long)DM * DM / 4);
  k_cvt_ck<<<4096, 256, 0, stream>>>(ck, Kb);

  // fused QKV projection: A=H [8192][1024], B=W-stack [3072][1024]
  k_gemm8<0><<<dim3(12, 32, 1), 512, 131072, stream>>>(
      Hb, Wall, Qb, Kb, Vtmp, nullptr, bq, bk, bv);

  // V^T
  k_build_vt<<<dim3(SKV / 64, DM / 64, NB), 256, 0, stream>>>(cv, Vtmp, VT);

  // S = QK^T with fused exp + row sums: A=Q, B=K, x=kv fastest (r3 traversal)
  hipMemsetAsync(sums, 0, (size_t)NB * SQN * 4, stream);
  k_gemm8<1><<<dim3(SKV / 256, SQN / 256, NB), 512, 131072, stream>>>(
      Qb, Kb, P, nullptr, nullptr, sums, nullptr, nullptr, nullptr);

  // PV split-K(2): A=P, B=VT
  k_gemm8<2><<<dim3(DM / 256, SQN / 256, NB * NSPLIT), 512, 131072, stream>>>(
      P, VT, Opart, nullptr, nullptr, nullptr, nullptr, nullptr, nullptr);

  // reduce partials + normalize
  k_reduce<<<(NB * SQN * DM / 4 + 255) / 256, 256, 0, stream>>>(
      Opart, sums, (float*)d_out);
}

// Round 13
// 439.169 us; speedup vs baseline: 1.4772x; 1.1740x over previous
//
#include <hip/hip_runtime.h>
#include <stdint.h>

// KVCacheAttention: B=4, Sq=2048, Scache=6144, Skv=8192, D=1024, scale=1/8.
// Round 13: m201-faithful quadrant-phase GEMM. 256x256xBK64, 8 waves (2Mx4N),
// 4 phases/K-tile; each phase: {ds_reads for THIS phase's quadrant issued
// PRE-barrier (cross-wave read||MFMA overlap) || stage 1 half-tile || vmcnt(4)
// || barrier || lgkm(0) || setprio + 16 MFMA}. Half-tile order [A0,B0,B1,A1];
// LDS [half][band][rows][64] so halves are gll16-linear; row&7 XOR swizzle.
// r8 operand orientation + epilogues (best total).

#define DM 1024
#define NB 4
#define SQN 2048
#define SCC 6144
#define SKV 8192
#define NSPLIT 2
#define KSP (SKV / NSPLIT)

typedef unsigned short u16;
typedef __attribute__((ext_vector_type(8))) short short8;
typedef __attribute__((ext_vector_type(4))) float f32x4;

__device__ __forceinline__ u16 f2bf(float x) {
  unsigned u = __builtin_bit_cast(unsigned, x);
  u += 0x7fffu + ((u >> 16) & 1u);  // RNE; inputs finite
  return (u16)(u >> 16);
}

__device__ __forceinline__ void gll16(const void* g, void* l) {
  __builtin_amdgcn_global_load_lds(
      (const __attribute__((address_space(1))) void*)g,
      (__attribute__((address_space(3))) void*)l, 16, 0, 0);
}

#define FENCE() asm volatile("" ::: "memory")
#define BARRIER()                      \
  do {                                 \
    FENCE();                           \
    __builtin_amdgcn_s_barrier();      \
    FENCE();                           \
  } while (0)

#define DSR(d, a, I) \
  asm volatile("ds_read_b128 %0, %1 offset:%2" : "=v"(d) : "v"(a), "i"(I))

#define VMC4() asm volatile("s_waitcnt vmcnt(4)" ::: "memory")
#define LGKM0()                                    \
  do {                                             \
    asm volatile("s_waitcnt lgkmcnt(0)" ::: "memory"); \
    __builtin_amdgcn_sched_barrier(0);             \
  } while (0)

// ---------------- conversions ----------------
__global__ __launch_bounds__(256) void k_cvt(const float* __restrict__ in,
                                             u16* __restrict__ out, long n4) {
  long i = (long)blockIdx.x * 256 + threadIdx.x;
  long st = (long)gridDim.x * 256;
  for (; i < n4; i += st) {
    float4 v = ((const float4*)in)[i];
    ushort4 u;
    u.x = f2bf(v.x); u.y = f2bf(v.y); u.z = f2bf(v.z); u.w = f2bf(v.w);
    ((ushort4*)out)[i] = u;
  }
}

// cached_key [4][6144][1024] f32 -> K bf16 [4][8192][1024] rows 0..6143
__global__ __launch_bounds__(256) void k_cvt_ck(const float* __restrict__ in,
                                                u16* __restrict__ out) {
  const long n4 = (long)NB * SCC * DM / 4;
  long i = (long)blockIdx.x * 256 + threadIdx.x;
  long st = (long)gridDim.x * 256;
  for (; i < n4; i += st) {
    float4 v = ((const float4*)in)[i];
    ushort4 u;
    u.x = f2bf(v.x); u.y = f2bf(v.y); u.z = f2bf(v.z); u.w = f2bf(v.w);
    long e = i * 4;
    int b = (int)(e / ((long)SCC * DM));
    long rem = e - (long)b * SCC * DM;
    *(ushort4*)(out + (long)b * SKV * DM + rem) = u;
  }
}

// ---------------- V^T builder ----------------
__global__ __launch_bounds__(256) void k_build_vt(const float* __restrict__ cv,
                                                  const u16* __restrict__ vtmp,
                                                  u16* __restrict__ VT) {
  __shared__ u16 t[64][65];
  const int kv0 = blockIdx.x * 64;
  const int d0 = blockIdx.y * 64;
  const int b = blockIdx.z;
  const int c = threadIdx.x & 63;
  const int r4 = threadIdx.x >> 6;
#pragma unroll
  for (int p = 0; p < 16; ++p) {
    int kr = p * 4 + r4;
    int kv = kv0 + kr;
    int d = d0 + c;
    u16 u;
    if (kv < SCC)
      u = f2bf(cv[((long)b * SCC + kv) * DM + d]);
    else
      u = vtmp[((long)b * SQN + (kv - SCC)) * DM + d];
    t[kr][c] = u;
  }
  __syncthreads();
#pragma unroll
  for (int p = 0; p < 16; ++p) {
    int dr = p * 4 + r4;
    VT[((long)b * DM + d0 + dr) * SKV + kv0 + c] = t[c][dr];
  }
}

// ---------------- 256x256xBK64 quadrant-phase NT GEMM ----------------
// 512 thr = 8 waves (2M x 4N); per-wave out 128x64.
// LDS 128 KiB: A[2buf][2half][128r][64k] @0, B same @65536.
// A-half mh = rows {wr*128 + mh*64 .. +64} for wr=0,1 -> LDS row' =
// mh*128 + wr*64 + r (gll16-linear, 2 loads/half). B-half nh analogous
// (row' = nh*128 + wc*32 + r). 16B slot ^= row'&7 via pre-swizzled source.
template <int MODE>
__global__ __launch_bounds__(512, 2) void k_gemm8(
    const u16* __restrict__ A, const u16* __restrict__ B0,
    void* __restrict__ C0, void* __restrict__ C1, void* __restrict__ C2,
    float* __restrict__ sums, const float* __restrict__ bias0,
    const float* __restrict__ bias1, const float* __restrict__ bias2) {
  extern __shared__ char smem[];
  const int tid = threadIdx.x;
  const int lane = tid & 63;
  const int wv = tid >> 6;   // 0..7
  const int wr = wv >> 2;    // 0..1
  const int wc = wv & 3;     // 0..3
  const int bm = blockIdx.y * 256;  // A rows
  const int bn = blockIdx.x * 256;  // B rows
  const int z = blockIdx.z;

  constexpr int LD = (MODE == 2) ? SKV : DM;
  constexpr int NT = ((MODE == 2) ? KSP : DM) / 64;

  const u16 *Ab_, *Bb_;
  if constexpr (MODE == 0) {
    Ab_ = A + (long)bm * LD;          // H tokens? (A=Wall here: out-d rows)
    Bb_ = B0 + (long)bn * LD;
  } else if constexpr (MODE == 1) {
    Ab_ = A + ((long)z * SKV + bm) * LD;   // K rows: kv
    Bb_ = B0 + ((long)z * SQN + bn) * LD;  // Q rows: q
  } else {
    const int bb_ = z / NSPLIT, sp = z % NSPLIT;
    Ab_ = A + ((long)bb_ * SQN + bm) * (long)SKV + (long)sp * KSP;
    Bb_ = B0 + ((long)bb_ * DM + bn) * (long)SKV + (long)sp * KSP;
  }

  // ---- staging addresses (per-lane global, linear LDS dest) ----
  const int sg = tid >> 3;                     // 0..63
  const int ssl = ((tid & 7) ^ (sg & 7)) * 8;  // pre-swizzled col (elems)
  const u16* gA[2][2];  // [mh][g]: grow = g*128 + mh*64 + sg
  const u16* gB[2][2];  // [nh][g]: grow = (g*2 + (sg>>5))*64 + nh*32 + (sg&31)
#pragma unroll
  for (int mh = 0; mh < 2; ++mh)
#pragma unroll
    for (int g = 0; g < 2; ++g) {
      gA[mh][g] = Ab_ + (long)(g * 128 + mh * 64 + sg) * LD + ssl;
      gB[mh][g] = Bb_ + (long)((g * 2 + (sg >> 5)) * 64 + mh * 32 + (sg & 31)) * LD + ssl;
    }
  u16* lA = (u16*)smem + tid * 8;           // + bufN*16384 + mh*8192 + g*4096
  u16* lB = (u16*)smem + 32768 + tid * 8;

#define SA(MH, BUFN, KO)                                              \
  do {                                                                \
    gll16(gA[MH][0] + (KO), lA + (BUFN)*16384 + (MH)*8192);           \
    gll16(gA[MH][1] + (KO), lA + (BUFN)*16384 + (MH)*8192 + 4096);    \
  } while (0)
#define SB(NH, BUFN, KO)                                              \
  do {                                                                \
    gll16(gB[NH][0] + (KO), lB + (BUFN)*16384 + (NH)*8192);           \
    gll16(gB[NH][1] + (KO), lB + (BUFN)*16384 + (NH)*8192 + 4096);    \
  } while (0)

  // prologue: stage tile 0 halves in order A0,B0,B1,A1; vmcnt(4) -> A0,B0 done
  SA(0, 0, 0);
  SB(0, 0, 0);
  SB(1, 0, 0);
  SA(1, 0, 0);
  VMC4();
  BARRIER();

  f32x4 acc[8][4];
#pragma unroll
  for (int m = 0; m < 8; ++m)
#pragma unroll
    for (int n = 0; n < 4; ++n)
#pragma unroll
      for (int j = 0; j < 4; ++j) acc[m][n][j] = 0.0f;

  const int alane = lane & 15;
  const int sw = lane & 7;
  const int s0 = lane >> 4;
  const int slot0 = ((s0 ^ sw) * 16);
  const int slot1 = (((s0 + 4) ^ sw) * 16);
  const int aBase = (wr * 64 + alane) * 128;  // + imm mh*16384 + ms*2048
  const int bBase = (wc * 32 + alane) * 128;  // + imm nh*16384 + ns*2048

  short8 aF[4][2];     // [ms][kk], current mh
  short8 bF[2][2][2];  // [nh][ns][kk], both halves live

#define ARD8(MH, AR0, AR1)                          \
  _Pragma("unroll") for (int ms = 0; ms < 4; ++ms) { \
    DSR(aF[ms][0], AR0, (MH)*16384 + ms * 2048);     \
    DSR(aF[ms][1], AR1, (MH)*16384 + ms * 2048);     \
  }
#define BRD4(NH, BR0, BR1)                          \
  _Pragma("unroll") for (int ns = 0; ns < 2; ++ns) { \
    DSR(bF[NH][ns][0], BR0, (NH)*16384 + ns * 2048); \
    DSR(bF[NH][ns][1], BR1, (NH)*16384 + ns * 2048); \
  }
#define MFMA_Q(MH, NH)                                                     \
  do {                                                                     \
    __builtin_amdgcn_s_setprio(1);                                         \
    _Pragma("unroll") for (int ms = 0; ms < 4; ++ms)                       \
    _Pragma("unroll") for (int ns = 0; ns < 2; ++ns)                       \
    _Pragma("unroll") for (int kk = 0; kk < 2; ++kk)                       \
        acc[(MH)*4 + ms][(NH)*2 + ns] =                                    \
            __builtin_amdgcn_mfma_f32_16x16x32_bf16(                       \
                aF[ms][kk], bF[NH][ns][kk], acc[(MH)*4 + ms][(NH)*2 + ns], \
                0, 0, 0);                                                  \
    __builtin_amdgcn_s_setprio(0);                                         \
    __builtin_amdgcn_sched_barrier(0);                                     \
  } while (0)

// One K-tile: 4 quadrant phases. Reads PRE-barrier (overlap with other
// waves' previous MFMA); stage order A0,B0,B1,A1 of tile KT+1 into buf^1;
// vmcnt(4) at phases 0,1,3 (RAW chains verified; never drains below 4).
#define TILE_BODY(BUF, KT)                                            \
  do {                                                                \
    const long ko = (long)(((KT) + 1 < NT) ? (KT) + 1 : (KT)) * 64;   \
    const int aR0 = (BUF)*32768 + aBase + slot0;                      \
    const int aR1 = (BUF)*32768 + aBase + slot1;                      \
    const int bR0 = 65536 + (BUF)*32768 + bBase + slot0;              \
    const int bR1 = 65536 + (BUF)*32768 + bBase + slot1;              \
    /* p0: Q(mh0,nh0) */                                              \
    ARD8(0, aR0, aR1);                                                \
    BRD4(0, bR0, bR1);                                                \
    SA(0, (BUF) ^ 1, ko);                                             \
    VMC4();                                                           \
    BARRIER();                                                        \
    LGKM0();                                                          \
    MFMA_Q(0, 0);                                                     \
    /* p1: Q(mh0,nh1) */                                              \
    BRD4(1, bR0, bR1);                                                \
    SB(0, (BUF) ^ 1, ko);                                             \
    VMC4();                                                           \
    BARRIER();                                                        \
    LGKM0();                                                          \
    MFMA_Q(0, 1);                                                     \
    /* p2: Q(mh1,nh1) */                                              \
    ARD8(1, aR0, aR1);                                                \
    SB(1, (BUF) ^ 1, ko);                                             \
    BARRIER();                                                        \
    LGKM0();                                                          \
    MFMA_Q(1, 1);                                                     \
    /* p3: Q(mh1,nh0) (all frags held) */                             \
    SA(1, (BUF) ^ 1, ko);                                             \
    VMC4();                                                           \
    BARRIER();                                                        \
    MFMA_Q(1, 0);                                                     \
  } while (0)

  for (int t2 = 0; t2 < NT; t2 += 2) {
    TILE_BODY(0, t2);
    TILE_BODY(1, t2 + 1);
  }
#undef TILE_BODY
#undef ARD8
#undef BRD4
#undef MFMA_Q
#undef SA
#undef SB

  // ---------------- epilogue (r8 verbatim; acc mapping identical) ----------
  const int rsub = (lane >> 4) * 4;

  if constexpr (MODE == 0) {
    // A=W-stack: acc row = out-d, col = token. which = bm>>10 per block.
    const int which = bm >> 10;
    const float* bp = which == 0 ? bias0 : (which == 1 ? bias1 : bias2);
    u16* Cq = (u16*)C0;
    u16* Ck = (u16*)C1;
    u16* Cv = (u16*)C2;
    const int od_base = (bm & 1023) + wr * 128 + rsub;
#pragma unroll
    for (int n = 0; n < 4; ++n) {
      int token = bn + wc * 64 + n * 16 + alane;
      u16* dst;
      if (which == 1) {
        int b = token >> 11, ss = token & 2047;
        dst = Ck + ((long)b * SKV + SCC + ss) * DM;
      } else if (which == 0) {
        dst = Cq + (long)token * DM;
      } else {
        dst = Cv + (long)token * DM;
      }
#pragma unroll
      for (int m = 0; m < 8; ++m) {
        int cc = od_base + m * 16;
        float4 bb = *(const float4*)(bp + cc);
        ushort4 u;
        u.x = f2bf(acc[m][n][0] + bb.x);
        u.y = f2bf(acc[m][n][1] + bb.y);
        u.z = f2bf(acc[m][n][2] + bb.z);
        u.w = f2bf(acc[m][n][3] + bb.w);
        *(ushort4*)(dst + cc) = u;
      }
    }
  } else if constexpr (MODE == 1) {
    // A=K: acc row = kv, col = q. store P[q][kv] ushort4; rowsum per q.
    u16* Pp = (u16*)C0 + (long)z * SQN * SKV;
    float* sb = sums + z * SQN;
    const float CE = 0.18033688011112042f;  // log2(e)/8
    const int kv_base = bm + wr * 128 + rsub;
#pragma unroll
    for (int n = 0; n < 4; ++n) {
      int q = bn + wc * 64 + n * 16 + alane;
      u16* prow = Pp + (long)q * SKV;
      float part = 0.f;
#pragma unroll
      for (int m = 0; m < 8; ++m) {
        int kv = kv_base + m * 16;
        float e0 = exp2f(acc[m][n][0] * CE);
        float e1 = exp2f(acc[m][n][1] * CE);
        float e2 = exp2f(acc[m][n][2] * CE);
        float e3 = exp2f(acc[m][n][3] * CE);
        part += (e0 + e1) + (e2 + e3);
        ushort4 u;
        u.x = f2bf(e0); u.y = f2bf(e1); u.z = f2bf(e2); u.w = f2bf(e3);
        *(ushort4*)(prow + kv) = u;
      }
      part += __shfl_xor(part, 16);
      part += __shfl_xor(part, 32);
      if ((lane >> 4) == 0) atomicAdd(&sb[q], part);
    }
  } else {
    // acc row = q, col = d. f32 stores, 64B sectors.
    float* Cp = (float*)C0 + (long)z * SQN * DM;
#pragma unroll
    for (int n = 0; n < 4; ++n) {
      int col = bn + wc * 64 + n * 16 + alane;
#pragma unroll
      for (int m = 0; m < 8; ++m)
#pragma unroll
        for (int j = 0; j < 4; ++j) {
          int row = bm + wr * 128 + m * 16 + rsub + j;
          Cp[(long)row * DM + col] = acc[m][n][j];
        }
    }
  }
}

// ---------------- reduce split-K partials + normalize ----------------
__global__ __launch_bounds__(256) void k_reduce(const float* __restrict__ Op,
                                                const float* __restrict__ sums,
                                                float* __restrict__ out) {
  const long n4 = (long)NB * SQN * DM / 4;
  long i = (long)blockIdx.x * 256 + threadIdx.x;
  if (i >= n4) return;
  long e = i * 4;
  int b = (int)(e / ((long)SQN * DM));
  long rem = e - (long)b * SQN * DM;
  int row = (int)(rem / DM);
  const long z4 = (long)SQN * DM / 4;
  long i0 = (long)(b * NSPLIT) * z4 + (rem >> 2);
  float4 a0 = ((const float4*)Op)[i0];
  float4 a1 = ((const float4*)Op)[i0 + z4];
  float inv = 1.0f / sums[b * SQN + row];
  float4 r;
  r.x = (a0.x + a1.x) * inv;
  r.y = (a0.y + a1.y) * inv;
  r.z = (a0.z + a1.z) * inv;
  r.w = (a0.w + a1.w) * inv;
  ((float4*)out)[i] = r;
}

// ---------------- launch ----------------
extern "C" void kernel_launch(void* const* d_in, const int* in_sizes, int n_in,
                              void* d_out, int out_size, void* d_ws, size_t ws_size,
                              hipStream_t stream) {
  const float* hidden = (const float*)d_in[0];
  const float* ck = (const float*)d_in[1];
  const float* cv = (const float*)d_in[2];
  const float* Wq = (const float*)d_in[3];
  const float* bq = (const float*)d_in[4];
  const float* Wk = (const float*)d_in[5];
  const float* bk = (const float*)d_in[6];
  const float* Wv = (const float*)d_in[7];
  const float* bv = (const float*)d_in[8];
  (void)in_sizes; (void)n_in; (void)out_size; (void)ws_size;

  hipFuncSetAttribute(reinterpret_cast<const void*>(&k_gemm8<0>),
                      hipFuncAttributeMaxDynamicSharedMemorySize, 131072);
  hipFuncSetAttribute(reinterpret_cast<const void*>(&k_gemm8<1>),
                      hipFuncAttributeMaxDynamicSharedMemorySize, 131072);
  hipFuncSetAttribute(reinterpret_cast<const void*>(&k_gemm8<2>),
                      hipFuncAttributeMaxDynamicSharedMemorySize, 131072);

  char* base = (char*)d_ws;
  size_t off = 0;
  auto alloc = [&](size_t bytes) {
    char* p = base + off;
    off = (off + bytes + 255) & ~(size_t)255;
    return p;
  };
  // region0 (dead before PV): Hb, weights, Qb, Kb, Vtmp. Opart aliases it.
  u16* Hb = (u16*)alloc((size_t)NB * SQN * DM * 2);
  u16* Wall = (u16*)alloc((size_t)3 * DM * DM * 2);  // Wq|Wk|Wv stacked
  u16* Qb = (u16*)alloc((size_t)NB * SQN * DM * 2);
  u16* Kb = (u16*)alloc((size_t)NB * SKV * DM * 2);
  u16* Vtmp = (u16*)alloc((size_t)NB * SQN * DM * 2);
  float* Opart = (float*)base;  // [NB*NSPLIT][2048][1024] f32, aliases region0
  size_t opart_bytes = (size_t)NB * NSPLIT * SQN * DM * 4;
  if (off < opart_bytes) off = (opart_bytes + 255) & ~(size_t)255;
  u16* VT = (u16*)alloc((size_t)NB * DM * SKV * 2);
  u16* P = (u16*)alloc((size_t)NB * SQN * SKV * 2);
  float* sums = (float*)alloc((size_t)NB * SQN * 4);

  // conversions
  k_cvt<<<2048, 256, 0, stream>>>(hidden, Hb, (long)NB * SQN * DM / 4);
  k_cvt<<<512, 256, 0, stream>>>(Wq, Wall, (long)DM * DM / 4);
  k_cvt<<<512, 256, 0, stream>>>(Wk, Wall + (size_t)DM * DM, (long)DM * DM / 4);
  k_cvt<<<512, 256, 0, stream>>>(Wv, Wall + (size_t)2 * DM * DM, (long)DM * DM / 4);
  k_cvt_ck<<<4096, 256, 0, stream>>>(ck, Kb);

  // fused QKV projection: A=W-stack [3072][1024], B=H [8192][1024]
  k_gemm8<0><<<dim3(32, 12, 1), 512, 131072, stream>>>(
      Wall, Hb, Qb, Kb, Vtmp, nullptr, bq, bk, bv);

  // V^T
  k_build_vt<<<dim3(SKV / 64, DM / 64, NB), 256, 0, stream>>>(cv, Vtmp, VT);

  // S^T = K.Q^T with fused exp + row sums (batched over 4): A=K, B=Q
  hipMemsetAsync(sums, 0, (size_t)NB * SQN * 4, stream);
  k_gemm8<1><<<dim3(SQN / 256, SKV / 256, NB), 512, 131072, stream>>>(
      Kb, Qb, P, nullptr, nullptr, sums, nullptr, nullptr, nullptr);

  // PV split-K(2): A=P, B=VT
  k_gemm8<2><<<dim3(DM / 256, SQN / 256, NB * NSPLIT), 512, 131072, stream>>>(
      P, VT, Opart, nullptr, nullptr, nullptr, nullptr, nullptr, nullptr);

  // reduce partials + normalize
  k_reduce<<<(NB * SQN * DM / 4 + 255) / 256, 256, 0, stream>>>(
      Opart, sums, (float*)d_out);
}